// Round 11
// baseline (1453.355 us; speedup 1.0000x reference)
//
#include <hip/hip_runtime.h>
#include <math.h>

constexpr int N = 50000;
constexpr int E = 800000;
constexpr int H = 64;
constexpr int NWAVE = 12500;          // N/4 nodes-per-wave mapping (4 nodes per wave)
constexpr int SCB = 49;               // scan blocks per graph: 49*1024 >= N
constexpr int RNG = 8;                // histogram ranges per graph
constexpr int BPR = 8;                // edge slices per graph
constexpr int BINS = N / RNG;         // 6250 bins per range
constexpr int ES   = E / BPR;         // 100000 edges per slice

typedef unsigned short ushort_t;
typedef unsigned int uint_t;
typedef unsigned char uchar_t;
typedef float fl2 __attribute__((ext_vector_type(2)));

// ---- workspace layout (element offsets) ----
constexpr size_t X_OFF    = 0;                          // N*H
constexpr size_t NO_OFF   = X_OFF + (size_t)N*H;        // N   deg_out^-1/2
constexpr size_t NI_OFF   = NO_OFF + N;                 // N   deg_in^-1/2
constexpr size_t EL_OFF   = NI_OFF + N;                 // N+1 GAT el (incl supernode)
constexpr size_t ER_OFF   = EL_OFF + (N+1);             // N   GAT er
constexpr size_t EE_OFF   = ER_OFF + N;                 // E   per-edge exp(e) (CSR order)
constexpr size_t IS_OFF   = EE_OFF + E;                 // N   1/softmax-denominator
constexpr size_t ASLF_OFF = IS_OFF + N;                 // N   self-loop numerator
constexpr size_t ASUP_OFF = ASLF_OFF + N;               // N   supernode numerator
constexpr size_t GF = ((ASUP_OFF + N + 255)/256)*256;

constexpr size_t RP_OFF = 0;                            // N+1 row_ptr (CSR by dst)
constexpr size_t CT_OFF = RP_OFF + (N+1);               // N   in-degree count
constexpr size_t SS_OFF = CT_OFF + N;                   // E   src sorted by dst
constexpr size_t GI = ((SS_OFF + E + 255)/256)*256;

// per-graph fp8 h block: 64 B per row (64 x e4m3); row N = supernode
constexpr size_t GH = (size_t)(N+1)*64;                 // in bytes

// fp8 helpers: HW RNE pack/unpack (OCP e4m3 on gfx950)
__device__ inline uint_t f8pack4(float a, float b, float c, float d){
  int r = __builtin_amdgcn_cvt_pk_fp8_f32(a, b, 0, false);
  r = __builtin_amdgcn_cvt_pk_fp8_f32(c, d, r, true);
  return (uint_t)r;
}
__device__ inline float f8val(uchar_t u){
  fl2 f = __builtin_amdgcn_cvt_pk_f32_fp8((int)u, false);
  return f.x;
}

// ---- prep: range-partitioned LDS histograms, zero global atomics ----
__global__ __launch_bounds__(1024) void k_hist(int* parts_ct, int* parts_no,
    const int* s0,const int* d0,const int* s1,const int* d1,const int* s2,const int* d2) {
  int sl = blockIdx.x, r = blockIdx.y, g = blockIdx.z;
  const int* s = g==0?s0:(g==1?s1:s2);
  const int* d = g==0?d0:(g==1?d1:d2);
  __shared__ int hc[BINS];
  __shared__ int hn[BINS];
  for (int i=threadIdx.x;i<BINS;i+=1024){ hc[i]=0; hn[i]=0; }
  __syncthreads();
  int lo = r*BINS, hi = lo+BINS;
  int e0 = sl*ES, e1 = e0+ES;
  for (int e=e0+threadIdx.x; e<e1; e+=1024){
    int ds = d[e], sr = s[e];
    if (ds>=lo && ds<hi) atomicAdd(&hc[ds-lo],1);
    if (sr>=lo && sr<hi) atomicAdd(&hn[sr-lo],1);
  }
  __syncthreads();
  size_t base = ((size_t)g*BPR + sl)*N + lo;
  for (int i=threadIdx.x;i<BINS;i+=1024){
    parts_ct[base+i]=hc[i];
    parts_no[base+i]=hn[i];
  }
}

// ---- hierarchical exclusive scan of cnt -> rp (all parallel) ----
__global__ __launch_bounds__(1024) void k_scan_local(int* ib, int* pt, const int* parts_ct) {
  int g = blockIdx.y;
  int* ig = ib + (size_t)g*GI;
  int i = blockIdx.x*1024 + threadIdx.x;
  int c = 0;
  if (i < N){
    #pragma unroll
    for (int s=0;s<BPR;s++) c += parts_ct[((size_t)g*BPR+s)*N + i];
    ig[CT_OFF + i] = c;
  }
  __shared__ int sh[1024];
  sh[threadIdx.x] = c; __syncthreads();
  #pragma unroll
  for (int off=1; off<1024; off<<=1){
    int t = (threadIdx.x>=off) ? sh[threadIdx.x-off] : 0;
    __syncthreads();
    sh[threadIdx.x] += t;
    __syncthreads();
  }
  if (i < N) ig[RP_OFF + i] = sh[threadIdx.x] - c;       // local exclusive
  if (threadIdx.x == 1023) pt[g*SCB + blockIdx.x] = sh[1023];
}

__global__ void k_scan_part(int* pt) {
  int g = blockIdx.x;
  __shared__ int sh[SCB];
  int t = threadIdx.x;
  if (t < SCB) sh[t] = pt[g*SCB + t];
  __syncthreads();
  if (t == 0){
    int run = 0;
    for (int b=0;b<SCB;b++){ int c = sh[b]; sh[b] = run; run += c; }
  }
  __syncthreads();
  if (t < SCB) pt[g*SCB + t] = sh[t];
}

__global__ __launch_bounds__(1024) void k_scan_apply(float* fb, int* ib, const int* pt,
                                                     const int* parts_no) {
  int g = blockIdx.y;
  float* fg = fb + (size_t)g*GF;
  int* ig = ib + (size_t)g*GI;
  int i = blockIdx.x*1024 + threadIdx.x;
  if (i >= N) return;
  int base = pt[g*SCB + blockIdx.x];
  int r = ig[RP_OFF + i] + base;
  ig[RP_OFF + i] = r;
  int c = ig[CT_OFF + i];
  int o = 0;
  #pragma unroll
  for (int s=0;s<BPR;s++) o += parts_no[((size_t)g*BPR+s)*N + i];
  fg[NI_OFF + i] = rsqrtf((float)(c+1));                 // +1 self loop
  fg[NO_OFF + i] = rsqrtf((float)(o+1));
  if (i == N-1) ig[RP_OFF + N] = r + c;
}

// per-(slice,bin) exclusive prefix over slices -> exact scatter offsets
__global__ __launch_bounds__(256) void k_slice_off(const int* ib, const int* parts_ct, int* off) {
  int g = blockIdx.y;
  int i = blockIdx.x*256 + threadIdx.x;
  if (i >= N) return;
  int base = ib[(size_t)g*GI + RP_OFF + i];
  #pragma unroll
  for (int s=0;s<BPR;s++){
    size_t idx = ((size_t)g*BPR+s)*N + i;
    off[idx] = base;
    base += parts_ct[idx];
  }
}

// scatter: LDS cursors per range, plain scattered store (no global atomics)
__global__ __launch_bounds__(1024) void k_scatter_r(int* ib, const int* off,
    const int* s0,const int* d0,const int* s1,const int* d1,const int* s2,const int* d2) {
  int sl = blockIdx.x, r = blockIdx.y, g = blockIdx.z;
  const int* s = g==0?s0:(g==1?s1:s2);
  const int* d = g==0?d0:(g==1?d1:d2);
  int* ss = ib + (size_t)g*GI + SS_OFF;
  __shared__ int cur[BINS];
  int lo = r*BINS;
  size_t ob = ((size_t)g*BPR + sl)*N + lo;
  for (int i=threadIdx.x;i<BINS;i+=1024) cur[i] = off[ob+i];
  __syncthreads();
  int e0 = sl*ES, e1 = e0+ES;
  for (int e=e0+threadIdx.x; e<e1; e+=1024){
    int ds = d[e];
    if (ds>=lo && ds<lo+BINS){
      int pos = atomicAdd(&cur[ds-lo],1);
      ss[pos] = s[e];
    }
  }
}

__global__ __launch_bounds__(256) void k_copyx(float* fb, const float* x0,const float* x1,const float* x2) {
  int i = blockIdx.x*256 + threadIdx.x;
  int g = blockIdx.y;
  const float* x = g==0?x0:(g==1?x1:x2);
  if (i < N*H/4) {
    ((float4*)(fb + (size_t)g*GF + X_OFF))[i] = ((const float4*)x)[i];
  }
}

// Tiled matmul: 64 rows/block, 4 threads/row (q = 16-col group), acc[16].
// h = fp8( (x @ W) * no[row] ) -> 64 B/row = 1 cache line per gather.
// Block (0,0) also zeroes readout accumulators.
__global__ __launch_bounds__(256) void k_mm_gcn(float* fb, uchar_t* hb,
    const float* W0,const float* W1,const float* W2, float* sm) {
  if (blockIdx.x==0 && blockIdx.y==0){
    for (int i=threadIdx.x;i<384;i+=256) sm[i]=0.f;
  }
  int g = blockIdx.y;
  const float* W = g==0?W0:(g==1?W1:W2);
  __shared__ float Ws[64*64];
  __shared__ float Xs[64*65];
  float* fg = fb + (size_t)g*GF;
  int row0 = blockIdx.x*64;
  for (int i=threadIdx.x; i<4096; i+=256) Ws[i] = W[i];
  int r = threadIdx.x>>2, q = threadIdx.x&3;
  int row = row0 + r;
  int rowc = row < N ? row : N-1;
  {
    const float4* xr = (const float4*)(fg + X_OFF + (size_t)rowc*64) + q*4;
    float* xd = Xs + r*65 + q*16;
    #pragma unroll
    for (int c=0;c<4;c++){ float4 v = xr[c]; xd[4*c]=v.x; xd[4*c+1]=v.y; xd[4*c+2]=v.z; xd[4*c+3]=v.w; }
  }
  __syncthreads();
  float acc[16];
  #pragma unroll
  for (int j=0;j<16;j++) acc[j]=0.f;
  const float* xrow = Xs + r*65;
  #pragma unroll 8
  for (int k=0;k<64;k++){
    float xk = xrow[k];
    const float* wr = Ws + k*64 + q*16;
    #pragma unroll
    for (int j=0;j<16;j++) acc[j] = fmaf(xk, wr[j], acc[j]);
  }
  if (row >= N) return;
  float sc = fg[NO_OFF + row];
  uint_t pk[4];
  #pragma unroll
  for (int j=0;j<4;j++)
    pk[j] = f8pack4(acc[4*j]*sc, acc[4*j+1]*sc, acc[4*j+2]*sc, acc[4*j+3]*sc);
  *(uint4*)(hb + (size_t)g*GH + (size_t)row*64 + q*16) = *(const uint4*)pk;
}

// Same tiling; h = fp8(x @ Wgat[g]); el/er via quad shfl reduce.
__global__ __launch_bounds__(256) void k_mm_gat(float* fb, uchar_t* hb,
    const float* Wgat, const float* al, const float* ar) {
  int g = blockIdx.y;
  const float* W = Wgat + (size_t)g*4096;
  __shared__ float Ws[64*64];
  __shared__ float Xs[64*65];
  __shared__ float als[64], ars[64];
  float* fg = fb + (size_t)g*GF;
  int row0 = blockIdx.x*64;
  for (int i=threadIdx.x; i<4096; i+=256) Ws[i] = W[i];
  if (threadIdx.x < 64){ als[threadIdx.x] = al[g*64+threadIdx.x]; ars[threadIdx.x] = ar[g*64+threadIdx.x]; }
  int r = threadIdx.x>>2, q = threadIdx.x&3;
  int row = row0 + r;
  int rowc = row < N ? row : N-1;
  {
    const float4* xr = (const float4*)(fg + X_OFF + (size_t)rowc*64) + q*4;
    float* xd = Xs + r*65 + q*16;
    #pragma unroll
    for (int c=0;c<4;c++){ float4 v = xr[c]; xd[4*c]=v.x; xd[4*c+1]=v.y; xd[4*c+2]=v.z; xd[4*c+3]=v.w; }
  }
  __syncthreads();
  float acc[16];
  #pragma unroll
  for (int j=0;j<16;j++) acc[j]=0.f;
  const float* xrow = Xs + r*65;
  #pragma unroll 8
  for (int k=0;k<64;k++){
    float xk = xrow[k];
    const float* wr = Ws + k*64 + q*16;
    #pragma unroll
    for (int j=0;j<16;j++) acc[j] = fmaf(xk, wr[j], acc[j]);
  }
  float el = 0.f, er = 0.f;
  #pragma unroll
  for (int j=0;j<16;j++){ el = fmaf(acc[j], als[q*16+j], el); er = fmaf(acc[j], ars[q*16+j], er); }
  el += __shfl_xor(el,1); el += __shfl_xor(el,2);
  er += __shfl_xor(er,1); er += __shfl_xor(er,2);
  if (row >= N) return;
  uint_t pk[4];
  #pragma unroll
  for (int j=0;j<4;j++)
    pk[j] = f8pack4(acc[4*j], acc[4*j+1], acc[4*j+2], acc[4*j+3]);
  *(uint4*)(hb + (size_t)g*GH + (size_t)row*64 + q*16) = *(const uint4*)pk;
  if (q == 0){
    fg[EL_OFF + row] = el;
    fg[ER_OFF + row] = er;
  }
}

// GCN aggregate + bias + relu -> new x ; fused mean/max readout.
// R5-proven structure; fp8 h: lane loads 1 byte, wave = 64 B = ONE line/edge.
__global__ __launch_bounds__(256) void k_gcn_agg(float* fb, const uchar_t* hb, const int* ib,
    const float* b, float* sm, int g) {
  float* fg = fb + (size_t)g*GF;
  const uchar_t* h = hb + (size_t)g*GH;
  const int* ig = ib + (size_t)g*GI;
  int wave = threadIdx.x >> 6, lane = threadIdx.x & 63;
  int w = blockIdx.x*4 + wave;
  const int* rp = ig + RP_OFF;
  const int* ss = ig + SS_OFF;
  float bl = b[lane];
  float vs = 0.f, vm = 0.f;
  #pragma unroll
  for (int i=0;i<4;i++){
    int node = w + NWAVE*i;
    float acc = f8val(h[(size_t)node*64 + lane]);   // self loop (pre-scaled)
    int s0 = rp[node], s1 = rp[node+1];
    int k = s0;
    for (; k + 8 <= s1; k += 8){
      int i0=ss[k],i1=ss[k+1],i2=ss[k+2],i3=ss[k+3];
      int i4=ss[k+4],i5=ss[k+5],i6=ss[k+6],i7=ss[k+7];
      uchar_t c0=h[(size_t)i0*64+lane], c1=h[(size_t)i1*64+lane];
      uchar_t c2=h[(size_t)i2*64+lane], c3=h[(size_t)i3*64+lane];
      uchar_t c4=h[(size_t)i4*64+lane], c5=h[(size_t)i5*64+lane];
      uchar_t c6=h[(size_t)i6*64+lane], c7=h[(size_t)i7*64+lane];
      acc += ((f8val(c0)+f8val(c1))+(f8val(c2)+f8val(c3)))
           + ((f8val(c4)+f8val(c5))+(f8val(c6)+f8val(c7)));
    }
    for (; k < s1; k++) acc += f8val(h[(size_t)ss[k]*64 + lane]);
    float v = acc * fg[NI_OFF+node] + bl;
    v = v > 0.f ? v : 0.f;
    fg[X_OFF + (size_t)node*64 + lane] = v;
    vs += v;
    vm = fmaxf(vm, v);
  }
  __shared__ float ssum[256];
  __shared__ float smax[256];
  ssum[threadIdx.x] = vs;
  smax[threadIdx.x] = vm;
  __syncthreads();
  if (threadIdx.x < 64){
    int lane2 = threadIdx.x;
    float s = ssum[lane2] + ssum[64+lane2] + ssum[128+lane2] + ssum[192+lane2];
    float mx = fmaxf(fmaxf(smax[lane2], smax[64+lane2]), fmaxf(smax[128+lane2], smax[192+lane2]));
    atomicAdd(&sm[g*64 + lane2], s);
    atomicMax((int*)sm + 192 + g*64 + lane2, __float_as_int(mx));  // v>=0: int order == float order
  }
}

// readout finalize + cross-graph feature exchange + supernode h row (fp8), el[N]
__global__ void k_exchange(float* fb, uchar_t* hb, float* sm, const float* Wx, const float* bx,
                           const float* Wgat, const float* al, int it) {
  int gt = blockIdx.x;     // target graph
  int t = threadIdx.x;     // 64 threads
  int src, widx;
  if ((it & 1) == 0){ src = (gt==0)?1:(gt==1)?2:0; widx = (gt==0)?1:(gt==1)?0:2; }
  else              { src = (gt==0)?2:(gt==1)?0:1; widx = (gt==0)?5:(gt==1)?3:4; }
  __shared__ float ro[128];
  __shared__ float f[64];
  __shared__ float red[64];
  __shared__ float hsb[64];
  ro[t]      = sm[src*64 + t] * (1.0f/(float)N);
  ro[64 + t] = __int_as_float(((int*)sm)[192 + src*64 + t]);
  __syncthreads();
  float a = bx[widx*64 + t];
  for (int k=0;k<128;k++) a = fmaf(ro[k], Wx[(size_t)widx*8192 + k*64 + t], a);
  a = a > 0.f ? a : 0.f;
  f[t] = a;
  __syncthreads();
  float* fg = fb + (size_t)gt*GF;
  float hs = 0.f;
  for (int k=0;k<64;k++) hs = fmaf(f[k], Wgat[(size_t)gt*4096 + k*64 + t], hs);
  hsb[t] = hs;
  red[t] = hs * al[gt*64 + t];
  __syncthreads();
  if (t < 16){
    uint_t r = f8pack4(hsb[4*t], hsb[4*t+1], hsb[4*t+2], hsb[4*t+3]);
    ((uint_t*)(hb + (size_t)gt*GH + (size_t)N*64))[t] = r;
  }
  if (t == 0){
    float e = 0.f;
    for (int k=0;k<64;k++) e += red[k];
    fg[EL_OFF + N] = e;                      // el for supernode
  }
}

// GAT softmax prep: wave per 4 nodes, lanes parallel over edges.
// Softmax computed without max-shift (|e| << 80, exact in fp32).
__global__ __launch_bounds__(256) void k_gat_prep(float* fb, const int* ib) {
  int g = blockIdx.y;
  float* fg = fb + (size_t)g*GF;
  const int* ig = ib + (size_t)g*GI;
  const int* rp = ig + RP_OFF;
  const int* ss = ig + SS_OFF;
  const float* el = fg + EL_OFF;
  float* ee = fg + EE_OFF;
  int wave = threadIdx.x>>6, lane = threadIdx.x&63;
  int w = blockIdx.x*4 + wave;
  float elsup = el[N];
  #pragma unroll
  for (int i=0;i<4;i++){
    int node = w + NWAVE*i;
    float eri = fg[ER_OFF + node];
    int s0 = rp[node], s1 = rp[node+1];
    float s = 0.f;
    for (int k=s0; k<s1; k+=64){
      int e = k + lane;
      float t = 0.f;
      if (e < s1){
        float x = el[ss[e]] + eri;
        x = x >= 0.f ? x : 0.2f*x;
        t = __expf(x);
        ee[e] = t;
      }
      s += t;
    }
    #pragma unroll
    for (int m=1;m<64;m<<=1) s += __shfl_xor(s,m);
    if (lane == 0){
      float eself = el[node] + eri; eself = eself >= 0.f ? eself : 0.2f*eself;
      float esup  = elsup + eri;    esup  = esup  >= 0.f ? esup  : 0.2f*esup;
      float ts = __expf(eself), tu = __expf(esup);
      s += ts + tu;
      fg[IS_OFF + node]   = 1.0f / s;
      fg[ASLF_OFF + node] = ts;
      fg[ASUP_OFF + node] = tu;
    }
  }
}

// GAT weighted aggregation -> new x ; fp8 byte gathers (1 line/edge).
__global__ __launch_bounds__(256) void k_gat_agg(float* fb, const uchar_t* hb, const int* ib,
    const float* bgat, int g) {
  float* fg = fb + (size_t)g*GF;
  const uchar_t* h = hb + (size_t)g*GH;
  const int* ig = ib + (size_t)g*GI;
  int wave = threadIdx.x >> 6, lane = threadIdx.x & 63;
  int w = blockIdx.x*4 + wave;
  const int* rp = ig + RP_OFF;
  const int* ss = ig + SS_OFF;
  const float* ee = fg + EE_OFF;
  float sup = f8val(h[(size_t)N*64 + lane]);
  float bl = bgat[g*64 + lane];
  #pragma unroll
  for (int i=0;i<4;i++){
    int node = w + NWAVE*i;
    float acc = fg[ASLF_OFF+node] * f8val(h[(size_t)node*64 + lane])
              + fg[ASUP_OFF+node] * sup;
    int s0 = rp[node], s1 = rp[node+1];
    int k = s0;
    for (; k + 8 <= s1; k += 8){
      int i0=ss[k],i1=ss[k+1],i2=ss[k+2],i3=ss[k+3];
      int i4=ss[k+4],i5=ss[k+5],i6=ss[k+6],i7=ss[k+7];
      float w0=ee[k],w1=ee[k+1],w2=ee[k+2],w3=ee[k+3];
      float w4=ee[k+4],w5=ee[k+5],w6=ee[k+6],w7=ee[k+7];
      uchar_t c0=h[(size_t)i0*64+lane], c1=h[(size_t)i1*64+lane];
      uchar_t c2=h[(size_t)i2*64+lane], c3=h[(size_t)i3*64+lane];
      uchar_t c4=h[(size_t)i4*64+lane], c5=h[(size_t)i5*64+lane];
      uchar_t c6=h[(size_t)i6*64+lane], c7=h[(size_t)i7*64+lane];
      float a0 = fmaf(w0, f8val(c0), w1 * f8val(c1));
      float a1 = fmaf(w2, f8val(c2), w3 * f8val(c3));
      float a2 = fmaf(w4, f8val(c4), w5 * f8val(c5));
      float a3 = fmaf(w6, f8val(c6), w7 * f8val(c7));
      acc += (a0+a1)+(a2+a3);
    }
    for (; k < s1; k++) acc = fmaf(ee[k], f8val(h[(size_t)ss[k]*64 + lane]), acc);
    fg[X_OFF + (size_t)node*64 + lane] = acc * fg[IS_OFF+node] + bl;
  }
}

__global__ __launch_bounds__(384) void k_mlp(const float* sm, const float* W1, const float* b1,
    const float* W2, const float* b2, const float* W3, const float* b3, float* out) {
  __shared__ float nf[384];
  __shared__ float y1[192];
  __shared__ float y2[96];
  __shared__ float z[2];
  int t = threadIdx.x;
  int g = t / 128, j = t % 128;
  nf[t] = (j < 64) ? sm[g*64 + j] * (1.0f/(float)N)
                   : __int_as_float(((const int*)sm)[192 + g*64 + (j-64)]);
  __syncthreads();
  if (t < 192){
    float a = b1[t];
    for (int k=0;k<384;k++) a = fmaf(nf[k], W1[(size_t)k*192 + t], a);
    y1[t] = a > 0.f ? a : 0.f;
  }
  __syncthreads();
  if (t < 96){
    float a = b2[t];
    for (int k=0;k<192;k++) a = fmaf(y1[k], W2[(size_t)k*96 + t], a);
    y2[t] = a > 0.f ? a : 0.f;
  }
  __syncthreads();
  if (t < 2){
    float a = b3[t];
    for (int k=0;k<96;k++) a = fmaf(y2[k], W3[k*2 + t], a);
    z[t] = a;
  }
  __syncthreads();
  if (t == 0){
    float m = fmaxf(z[0], z[1]);
    float l = m + logf(__expf(z[0]-m) + __expf(z[1]-m));
    out[0] = z[0] - l;
    out[1] = z[1] - l;
  }
}

extern "C" void kernel_launch(void* const* d_in, const int* in_sizes, int n_in,
                              void* d_out, int out_size, void* d_ws, size_t ws_size,
                              hipStream_t stream) {
  const float* x_s  = (const float*)d_in[0];
  const float* x_g  = (const float*)d_in[1];
  const float* x_t  = (const float*)d_in[2];
  const float* Wc_s = (const float*)d_in[3];
  const float* bc_s = (const float*)d_in[4];
  const float* Wc_g = (const float*)d_in[5];
  const float* bc_g = (const float*)d_in[6];
  const float* Wc_t = (const float*)d_in[7];
  const float* bc_t = (const float*)d_in[8];
  const float* Wx   = (const float*)d_in[9];
  const float* bx   = (const float*)d_in[10];
  const float* Wgat = (const float*)d_in[11];
  const float* al   = (const float*)d_in[12];
  const float* ar   = (const float*)d_in[13];
  const float* bgat = (const float*)d_in[14];
  const float* W1   = (const float*)d_in[15];
  const float* b1   = (const float*)d_in[16];
  const float* W2   = (const float*)d_in[17];
  const float* b2   = (const float*)d_in[18];
  const float* W3   = (const float*)d_in[19];
  const float* b3   = (const float*)d_in[20];
  const int* src_s  = (const int*)d_in[21];
  const int* dst_s  = (const int*)d_in[22];
  const int* src_g  = (const int*)d_in[23];
  const int* dst_g  = (const int*)d_in[24];
  const int* src_t  = (const int*)d_in[25];
  const int* dst_t  = (const int*)d_in[26];

  float* fb = (float*)d_ws;
  int*   ib = (int*)(fb + 3*GF);
  uchar_t* hb = (uchar_t*)(ib + 3*GI);
  float* sm = (float*)(hb + 3*GH);
  int*   pt = (int*)(sm + 384);              // 3*SCB scan partials
  int*   parts_ct = pt + 3*SCB + 64;         // 3*BPR*N
  int*   parts_no = parts_ct + (size_t)3*BPR*N;
  int*   off      = parts_no + (size_t)3*BPR*N;
  float* out = (float*)d_out;

  dim3 b256(256);
  const float* bcs[3][3] = {{bc_s, bc_g, bc_t},{bc_s+64, bc_g+64, bc_t+64},{bc_s+128, bc_g+128, bc_t+128}};
  int mmb = (N+63)/64;

  // graph prep: LDS-histogram counting sort (no global atomics)
  k_hist      <<<dim3(BPR, RNG, 3),  dim3(1024), 0, stream>>>(parts_ct, parts_no, src_s,dst_s, src_g,dst_g, src_t,dst_t);
  k_scan_local<<<dim3(SCB, 3),       dim3(1024), 0, stream>>>(ib, pt, parts_ct);
  k_scan_part <<<dim3(3),              dim3(64), 0, stream>>>(pt);
  k_scan_apply<<<dim3(SCB, 3),       dim3(1024), 0, stream>>>(fb, ib, pt, parts_no);
  k_slice_off <<<dim3((N+255)/256, 3),     b256, 0, stream>>>(ib, parts_ct, off);
  k_scatter_r <<<dim3(BPR, RNG, 3),  dim3(1024), 0, stream>>>(ib, off, src_s,dst_s, src_g,dst_g, src_t,dst_t);
  k_copyx     <<<dim3((N*H/4+255)/256, 3), b256, 0, stream>>>(fb, x_s, x_g, x_t);

  for (int it = 0; it < 2; ++it) {
    k_mm_gcn  <<<dim3(mmb, 3), b256, 0, stream>>>(fb, hb, Wc_s + it*4096, Wc_g + it*4096, Wc_t + it*4096, sm);
    for (int g = 0; g < 3; ++g)
      k_gcn_agg <<<dim3(NWAVE/4), b256, 0, stream>>>(fb, hb, ib, bcs[it][g], sm, g);
    k_exchange<<<dim3(3), dim3(64), 0, stream>>>(fb, hb, sm, Wx, bx, Wgat, al, it);
    k_mm_gat  <<<dim3(mmb, 3), b256, 0, stream>>>(fb, hb, Wgat, al, ar);
    k_gat_prep<<<dim3(NWAVE/4, 3), b256, 0, stream>>>(fb, ib);
    for (int g = 0; g < 3; ++g)
      k_gat_agg <<<dim3(NWAVE/4), b256, 0, stream>>>(fb, hb, ib, bgat, g);
  }

  // final layer readouts + MLP head
  k_mm_gcn  <<<dim3(mmb, 3), b256, 0, stream>>>(fb, hb, Wc_s + 2*4096, Wc_g + 2*4096, Wc_t + 2*4096, sm);
  for (int g = 0; g < 3; ++g)
    k_gcn_agg <<<dim3(NWAVE/4), b256, 0, stream>>>(fb, hb, ib, bcs[2][g], sm, g);
  k_mlp     <<<1, 384, 0, stream>>>(sm, W1, b1, W2, b2, W3, b3, out);
}

// Round 12
// 1191.386 us; speedup vs baseline: 1.2199x; 1.2199x over previous
//
#include <hip/hip_runtime.h>
#include <math.h>

constexpr int N = 50000;
constexpr int E = 800000;
constexpr int H = 64;
constexpr int NWAVE = 12500;          // N/4 nodes-per-wave mapping (4 nodes per wave)
constexpr int SCB = 49;               // scan blocks per graph: 49*1024 >= N
constexpr int RNG = 8;                // histogram ranges per graph
constexpr int BPR = 8;                // edge slices per graph
constexpr int BINS = N / RNG;         // 6250 bins per range
constexpr int ES   = E / BPR;         // 100000 edges per slice

typedef unsigned short ushort_t;
typedef unsigned int uint_t;

// ---- workspace layout (element offsets) ----
constexpr size_t X_OFF    = 0;                          // N*H
constexpr size_t NO_OFF   = X_OFF + (size_t)N*H;        // N   deg_out^-1/2
constexpr size_t NI_OFF   = NO_OFF + N;                 // N   deg_in^-1/2
constexpr size_t EL_OFF   = NI_OFF + N;                 // N+1 GAT el (incl supernode)
constexpr size_t ER_OFF   = EL_OFF + (N+1);             // N   GAT er
constexpr size_t EE_OFF   = ER_OFF + N;                 // E   per-edge exp(e) (CSR order)
constexpr size_t IS_OFF   = EE_OFF + E;                 // N   1/softmax-denominator
constexpr size_t ASLF_OFF = IS_OFF + N;                 // N   self-loop numerator
constexpr size_t ASUP_OFF = ASLF_OFF + N;               // N   supernode numerator
constexpr size_t GF = ((ASUP_OFF + N + 255)/256)*256;

constexpr size_t RP_OFF = 0;                            // N+1 row_ptr (CSR by dst)
constexpr size_t CT_OFF = RP_OFF + (N+1);               // N   in-degree count
constexpr size_t SS_OFF = CT_OFF + N;                   // E   src sorted by dst
constexpr size_t GI = ((SS_OFF + E + 255)/256)*256;

// per-graph bf16 h block (row N = supernode), 64 ushorts per row
constexpr size_t GH = (size_t)(N+1)*64;

// bf16 helpers (RNE)
__device__ inline uint_t bfpack2(float a, float b){
  uint_t ua=__float_as_uint(a), ub=__float_as_uint(b);
  uint_t ra=(ua + 0x7fffu + ((ua>>16)&1u))>>16;
  uint_t rb=(ub + 0x7fffu + ((ub>>16)&1u))>>16;
  return ra | (rb<<16);
}
__device__ inline float bf2f(ushort_t u){ return __uint_as_float(((uint_t)u)<<16); }

// ---- prep: range-partitioned LDS histograms, zero global atomics ----
__global__ __launch_bounds__(1024) void k_hist(int* parts_ct, int* parts_no,
    const int* s0,const int* d0,const int* s1,const int* d1,const int* s2,const int* d2) {
  int sl = blockIdx.x, r = blockIdx.y, g = blockIdx.z;
  const int* s = g==0?s0:(g==1?s1:s2);
  const int* d = g==0?d0:(g==1?d1:d2);
  __shared__ int hc[BINS];
  __shared__ int hn[BINS];
  for (int i=threadIdx.x;i<BINS;i+=1024){ hc[i]=0; hn[i]=0; }
  __syncthreads();
  int lo = r*BINS, hi = lo+BINS;
  int e0 = sl*ES, e1 = e0+ES;
  for (int e=e0+threadIdx.x; e<e1; e+=1024){
    int ds = d[e], sr = s[e];
    if (ds>=lo && ds<hi) atomicAdd(&hc[ds-lo],1);
    if (sr>=lo && sr<hi) atomicAdd(&hn[sr-lo],1);
  }
  __syncthreads();
  size_t base = ((size_t)g*BPR + sl)*N + lo;
  for (int i=threadIdx.x;i<BINS;i+=1024){
    parts_ct[base+i]=hc[i];
    parts_no[base+i]=hn[i];
  }
}

// ---- hierarchical exclusive scan of cnt -> rp (all parallel) ----
__global__ __launch_bounds__(1024) void k_scan_local(int* ib, int* pt, const int* parts_ct) {
  int g = blockIdx.y;
  int* ig = ib + (size_t)g*GI;
  int i = blockIdx.x*1024 + threadIdx.x;
  int c = 0;
  if (i < N){
    #pragma unroll
    for (int s=0;s<BPR;s++) c += parts_ct[((size_t)g*BPR+s)*N + i];
    ig[CT_OFF + i] = c;
  }
  __shared__ int sh[1024];
  sh[threadIdx.x] = c; __syncthreads();
  #pragma unroll
  for (int off=1; off<1024; off<<=1){
    int t = (threadIdx.x>=off) ? sh[threadIdx.x-off] : 0;
    __syncthreads();
    sh[threadIdx.x] += t;
    __syncthreads();
  }
  if (i < N) ig[RP_OFF + i] = sh[threadIdx.x] - c;       // local exclusive
  if (threadIdx.x == 1023) pt[g*SCB + blockIdx.x] = sh[1023];
}

__global__ void k_scan_part(int* pt) {
  int g = blockIdx.x;
  __shared__ int sh[SCB];
  int t = threadIdx.x;
  if (t < SCB) sh[t] = pt[g*SCB + t];
  __syncthreads();
  if (t == 0){
    int run = 0;
    for (int b=0;b<SCB;b++){ int c = sh[b]; sh[b] = run; run += c; }
  }
  __syncthreads();
  if (t < SCB) pt[g*SCB + t] = sh[t];
}

__global__ __launch_bounds__(1024) void k_scan_apply(float* fb, int* ib, const int* pt,
                                                     const int* parts_no) {
  int g = blockIdx.y;
  float* fg = fb + (size_t)g*GF;
  int* ig = ib + (size_t)g*GI;
  int i = blockIdx.x*1024 + threadIdx.x;
  if (i >= N) return;
  int base = pt[g*SCB + blockIdx.x];
  int r = ig[RP_OFF + i] + base;
  ig[RP_OFF + i] = r;
  int c = ig[CT_OFF + i];
  int o = 0;
  #pragma unroll
  for (int s=0;s<BPR;s++) o += parts_no[((size_t)g*BPR+s)*N + i];
  fg[NI_OFF + i] = rsqrtf((float)(c+1));                 // +1 self loop
  fg[NO_OFF + i] = rsqrtf((float)(o+1));
  if (i == N-1) ig[RP_OFF + N] = r + c;
}

// per-(slice,bin) exclusive prefix over slices -> exact scatter offsets
__global__ __launch_bounds__(256) void k_slice_off(const int* ib, const int* parts_ct, int* off) {
  int g = blockIdx.y;
  int i = blockIdx.x*256 + threadIdx.x;
  if (i >= N) return;
  int base = ib[(size_t)g*GI + RP_OFF + i];
  #pragma unroll
  for (int s=0;s<BPR;s++){
    size_t idx = ((size_t)g*BPR+s)*N + i;
    off[idx] = base;
    base += parts_ct[idx];
  }
}

// scatter: LDS cursors per range, plain scattered store (no global atomics)
__global__ __launch_bounds__(1024) void k_scatter_r(int* ib, const int* off,
    const int* s0,const int* d0,const int* s1,const int* d1,const int* s2,const int* d2) {
  int sl = blockIdx.x, r = blockIdx.y, g = blockIdx.z;
  const int* s = g==0?s0:(g==1?s1:s2);
  const int* d = g==0?d0:(g==1?d1:d2);
  int* ss = ib + (size_t)g*GI + SS_OFF;
  __shared__ int cur[BINS];
  int lo = r*BINS;
  size_t ob = ((size_t)g*BPR + sl)*N + lo;
  for (int i=threadIdx.x;i<BINS;i+=1024) cur[i] = off[ob+i];
  __syncthreads();
  int e0 = sl*ES, e1 = e0+ES;
  for (int e=e0+threadIdx.x; e<e1; e+=1024){
    int ds = d[e];
    if (ds>=lo && ds<lo+BINS){
      int pos = atomicAdd(&cur[ds-lo],1);
      ss[pos] = s[e];
    }
  }
}

__global__ __launch_bounds__(256) void k_copyx(float* fb, const float* x0,const float* x1,const float* x2) {
  int i = blockIdx.x*256 + threadIdx.x;
  int g = blockIdx.y;
  const float* x = g==0?x0:(g==1?x1:x2);
  if (i < N*H/4) {
    ((float4*)(fb + (size_t)g*GF + X_OFF))[i] = ((const float4*)x)[i];
  }
}

// Tiled matmul: 64 rows/block, 4 threads/row (q = 16-col group), acc[16].
// X tile staged in padded LDS; W in LDS. h = bf16((x @ W) * no[row]).
// Block (0,0) also zeroes readout accumulators.
__global__ __launch_bounds__(256) void k_mm_gcn(float* fb, ushort_t* hb,
    const float* W0,const float* W1,const float* W2, float* sm) {
  if (blockIdx.x==0 && blockIdx.y==0){
    for (int i=threadIdx.x;i<384;i+=256) sm[i]=0.f;
  }
  int g = blockIdx.y;
  const float* W = g==0?W0:(g==1?W1:W2);
  __shared__ float Ws[64*64];
  __shared__ float Xs[64*65];
  float* fg = fb + (size_t)g*GF;
  int row0 = blockIdx.x*64;
  for (int i=threadIdx.x; i<4096; i+=256) Ws[i] = W[i];
  int r = threadIdx.x>>2, q = threadIdx.x&3;
  int row = row0 + r;
  int rowc = row < N ? row : N-1;
  {
    const float4* xr = (const float4*)(fg + X_OFF + (size_t)rowc*64) + q*4;
    float* xd = Xs + r*65 + q*16;
    #pragma unroll
    for (int c=0;c<4;c++){ float4 v = xr[c]; xd[4*c]=v.x; xd[4*c+1]=v.y; xd[4*c+2]=v.z; xd[4*c+3]=v.w; }
  }
  __syncthreads();
  float acc[16];
  #pragma unroll
  for (int j=0;j<16;j++) acc[j]=0.f;
  const float* xrow = Xs + r*65;
  #pragma unroll 8
  for (int k=0;k<64;k++){
    float xk = xrow[k];
    const float* wr = Ws + k*64 + q*16;
    #pragma unroll
    for (int j=0;j<16;j++) acc[j] = fmaf(xk, wr[j], acc[j]);
  }
  if (row >= N) return;
  float sc = fg[NO_OFF + row];
  uint_t pk[8];
  #pragma unroll
  for (int j=0;j<8;j++) pk[j] = bfpack2(acc[2*j]*sc, acc[2*j+1]*sc);
  uint4* hd = (uint4*)(hb + (size_t)g*GH + (size_t)row*64 + q*16);
  hd[0] = ((const uint4*)pk)[0];
  hd[1] = ((const uint4*)pk)[1];
}

// Same tiling; h = bf16(x @ Wgat[g]); el/er via quad shfl reduce.
__global__ __launch_bounds__(256) void k_mm_gat(float* fb, ushort_t* hb,
    const float* Wgat, const float* al, const float* ar) {
  int g = blockIdx.y;
  const float* W = Wgat + (size_t)g*4096;
  __shared__ float Ws[64*64];
  __shared__ float Xs[64*65];
  __shared__ float als[64], ars[64];
  float* fg = fb + (size_t)g*GF;
  int row0 = blockIdx.x*64;
  for (int i=threadIdx.x; i<4096; i+=256) Ws[i] = W[i];
  if (threadIdx.x < 64){ als[threadIdx.x] = al[g*64+threadIdx.x]; ars[threadIdx.x] = ar[g*64+threadIdx.x]; }
  int r = threadIdx.x>>2, q = threadIdx.x&3;
  int row = row0 + r;
  int rowc = row < N ? row : N-1;
  {
    const float4* xr = (const float4*)(fg + X_OFF + (size_t)rowc*64) + q*4;
    float* xd = Xs + r*65 + q*16;
    #pragma unroll
    for (int c=0;c<4;c++){ float4 v = xr[c]; xd[4*c]=v.x; xd[4*c+1]=v.y; xd[4*c+2]=v.z; xd[4*c+3]=v.w; }
  }
  __syncthreads();
  float acc[16];
  #pragma unroll
  for (int j=0;j<16;j++) acc[j]=0.f;
  const float* xrow = Xs + r*65;
  #pragma unroll 8
  for (int k=0;k<64;k++){
    float xk = xrow[k];
    const float* wr = Ws + k*64 + q*16;
    #pragma unroll
    for (int j=0;j<16;j++) acc[j] = fmaf(xk, wr[j], acc[j]);
  }
  float el = 0.f, er = 0.f;
  #pragma unroll
  for (int j=0;j<16;j++){ el = fmaf(acc[j], als[q*16+j], el); er = fmaf(acc[j], ars[q*16+j], er); }
  el += __shfl_xor(el,1); el += __shfl_xor(el,2);
  er += __shfl_xor(er,1); er += __shfl_xor(er,2);
  if (row >= N) return;
  uint_t pk[8];
  #pragma unroll
  for (int j=0;j<8;j++) pk[j] = bfpack2(acc[2*j], acc[2*j+1]);
  uint4* hd = (uint4*)(hb + (size_t)g*GH + (size_t)row*64 + q*16);
  hd[0] = ((const uint4*)pk)[0];
  hd[1] = ((const uint4*)pk)[1];
  if (q == 0){
    fg[EL_OFF + row] = el;
    fg[ER_OFF + row] = er;
  }
}

// GCN aggregate + bias + relu -> new x ; fused mean/max readout.
// MERGED over graphs: grid (NWAVE/4, 3); 4 nodes per wave; 8-unrolled gathers.
// writex=0 on the final layer (only readout consumed).
__global__ __launch_bounds__(256) void k_gcn_agg(float* fb, const ushort_t* hb, const int* ib,
    const float* b0, const float* b1, const float* b2, int lay, float* sm, int writex) {
  int g = blockIdx.y;
  const float* b = (g==0?b0:(g==1?b1:b2)) + lay*64;
  float* fg = fb + (size_t)g*GF;
  const ushort_t* h = hb + (size_t)g*GH;
  const int* ig = ib + (size_t)g*GI;
  int wave = threadIdx.x >> 6, lane = threadIdx.x & 63;
  int w = blockIdx.x*4 + wave;
  const int* rp = ig + RP_OFF;
  const int* ss = ig + SS_OFF;
  float bl = b[lane];
  float vs = 0.f, vm = 0.f;
  #pragma unroll
  for (int i=0;i<4;i++){
    int node = w + NWAVE*i;
    float acc = bf2f(h[(size_t)node*64 + lane]);   // self loop (pre-scaled)
    int s0 = rp[node], s1 = rp[node+1];
    int k = s0;
    for (; k + 8 <= s1; k += 8){
      int i0=ss[k],i1=ss[k+1],i2=ss[k+2],i3=ss[k+3];
      int i4=ss[k+4],i5=ss[k+5],i6=ss[k+6],i7=ss[k+7];
      float v0=bf2f(h[(size_t)i0*64+lane]), v1=bf2f(h[(size_t)i1*64+lane]);
      float v2=bf2f(h[(size_t)i2*64+lane]), v3=bf2f(h[(size_t)i3*64+lane]);
      float v4=bf2f(h[(size_t)i4*64+lane]), v5=bf2f(h[(size_t)i5*64+lane]);
      float v6=bf2f(h[(size_t)i6*64+lane]), v7=bf2f(h[(size_t)i7*64+lane]);
      acc += ((v0+v1)+(v2+v3)) + ((v4+v5)+(v6+v7));
    }
    for (; k < s1; k++) acc += bf2f(h[(size_t)ss[k]*64 + lane]);
    float v = acc * fg[NI_OFF+node] + bl;
    v = v > 0.f ? v : 0.f;
    if (writex) fg[X_OFF + (size_t)node*64 + lane] = v;
    vs += v;
    vm = fmaxf(vm, v);
  }
  __shared__ float ssum[256];
  __shared__ float smax[256];
  ssum[threadIdx.x] = vs;
  smax[threadIdx.x] = vm;
  __syncthreads();
  if (threadIdx.x < 64){
    int lane2 = threadIdx.x;
    float s = ssum[lane2] + ssum[64+lane2] + ssum[128+lane2] + ssum[192+lane2];
    float mx = fmaxf(fmaxf(smax[lane2], smax[64+lane2]), fmaxf(smax[128+lane2], smax[192+lane2]));
    atomicAdd(&sm[g*64 + lane2], s);
    atomicMax((int*)sm + 192 + g*64 + lane2, __float_as_int(mx));  // v>=0: int order == float order
  }
}

// readout finalize + cross-graph feature exchange + supernode h row (bf16), el[N]
__global__ void k_exchange(float* fb, ushort_t* hb, float* sm, const float* Wx, const float* bx,
                           const float* Wgat, const float* al, int it) {
  int gt = blockIdx.x;     // target graph
  int t = threadIdx.x;     // 64 threads
  int src, widx;
  if ((it & 1) == 0){ src = (gt==0)?1:(gt==1)?2:0; widx = (gt==0)?1:(gt==1)?0:2; }
  else              { src = (gt==0)?2:(gt==1)?0:1; widx = (gt==0)?5:(gt==1)?3:4; }
  __shared__ float ro[128];
  __shared__ float f[64];
  __shared__ float red[64];
  ro[t]      = sm[src*64 + t] * (1.0f/(float)N);
  ro[64 + t] = __int_as_float(((int*)sm)[192 + src*64 + t]);
  __syncthreads();
  float a = bx[widx*64 + t];
  for (int k=0;k<128;k++) a = fmaf(ro[k], Wx[(size_t)widx*8192 + k*64 + t], a);
  a = a > 0.f ? a : 0.f;
  f[t] = a;
  __syncthreads();
  float* fg = fb + (size_t)gt*GF;
  float hs = 0.f;
  for (int k=0;k<64;k++) hs = fmaf(f[k], Wgat[(size_t)gt*4096 + k*64 + t], hs);
  uint_t u = __float_as_uint(hs);
  hb[(size_t)gt*GH + (size_t)N*64 + t] = (ushort_t)((u + 0x7fffu + ((u>>16)&1u))>>16);
  red[t] = hs * al[gt*64 + t];
  __syncthreads();
  if (t == 0){
    float e = 0.f;
    for (int k=0;k<64;k++) e += red[k];
    fg[EL_OFF + N] = e;                      // el for supernode
  }
}

// GAT softmax prep: wave per 4 nodes, lanes parallel over edges.
// Softmax computed without max-shift (|e| << 80, exact in fp32).
__global__ __launch_bounds__(256) void k_gat_prep(float* fb, const int* ib) {
  int g = blockIdx.y;
  float* fg = fb + (size_t)g*GF;
  const int* ig = ib + (size_t)g*GI;
  const int* rp = ig + RP_OFF;
  const int* ss = ig + SS_OFF;
  const float* el = fg + EL_OFF;
  float* ee = fg + EE_OFF;
  int wave = threadIdx.x>>6, lane = threadIdx.x&63;
  int w = blockIdx.x*4 + wave;
  float elsup = el[N];
  #pragma unroll
  for (int i=0;i<4;i++){
    int node = w + NWAVE*i;
    float eri = fg[ER_OFF + node];
    int s0 = rp[node], s1 = rp[node+1];
    float s = 0.f;
    for (int k=s0; k<s1; k+=64){
      int e = k + lane;
      float t = 0.f;
      if (e < s1){
        float x = el[ss[e]] + eri;
        x = x >= 0.f ? x : 0.2f*x;
        t = __expf(x);
        ee[e] = t;
      }
      s += t;
    }
    #pragma unroll
    for (int m=1;m<64;m<<=1) s += __shfl_xor(s,m);
    if (lane == 0){
      float eself = el[node] + eri; eself = eself >= 0.f ? eself : 0.2f*eself;
      float esup  = elsup + eri;    esup  = esup  >= 0.f ? esup  : 0.2f*esup;
      float ts = __expf(eself), tu = __expf(esup);
      s += ts + tu;
      fg[IS_OFF + node]   = 1.0f / s;
      fg[ASLF_OFF + node] = ts;
      fg[ASUP_OFF + node] = tu;
    }
  }
}

// GAT weighted aggregation -> new x ; MERGED over graphs: grid (NWAVE/4, 3).
__global__ __launch_bounds__(256) void k_gat_agg(float* fb, const ushort_t* hb, const int* ib,
    const float* bgat) {
  int g = blockIdx.y;
  float* fg = fb + (size_t)g*GF;
  const ushort_t* h = hb + (size_t)g*GH;
  const int* ig = ib + (size_t)g*GI;
  int wave = threadIdx.x >> 6, lane = threadIdx.x & 63;
  int w = blockIdx.x*4 + wave;
  const int* rp = ig + RP_OFF;
  const int* ss = ig + SS_OFF;
  const float* ee = fg + EE_OFF;
  float sup = bf2f(h[(size_t)N*64 + lane]);
  float bl = bgat[g*64 + lane];
  #pragma unroll
  for (int i=0;i<4;i++){
    int node = w + NWAVE*i;
    float acc = fg[ASLF_OFF+node] * bf2f(h[(size_t)node*64 + lane])
              + fg[ASUP_OFF+node] * sup;
    int s0 = rp[node], s1 = rp[node+1];
    int k = s0;
    for (; k + 8 <= s1; k += 8){
      int i0=ss[k],i1=ss[k+1],i2=ss[k+2],i3=ss[k+3];
      int i4=ss[k+4],i5=ss[k+5],i6=ss[k+6],i7=ss[k+7];
      float w0=ee[k],w1=ee[k+1],w2=ee[k+2],w3=ee[k+3];
      float w4=ee[k+4],w5=ee[k+5],w6=ee[k+6],w7=ee[k+7];
      float a0 = fmaf(w0, bf2f(h[(size_t)i0*64+lane]), w1 * bf2f(h[(size_t)i1*64+lane]));
      float a1 = fmaf(w2, bf2f(h[(size_t)i2*64+lane]), w3 * bf2f(h[(size_t)i3*64+lane]));
      float a2 = fmaf(w4, bf2f(h[(size_t)i4*64+lane]), w5 * bf2f(h[(size_t)i5*64+lane]));
      float a3 = fmaf(w6, bf2f(h[(size_t)i6*64+lane]), w7 * bf2f(h[(size_t)i7*64+lane]));
      acc += (a0+a1)+(a2+a3);
    }
    for (; k < s1; k++) acc = fmaf(ee[k], bf2f(h[(size_t)ss[k]*64 + lane]), acc);
    fg[X_OFF + (size_t)node*64 + lane] = acc * fg[IS_OFF+node] + bl;
  }
}

__global__ __launch_bounds__(384) void k_mlp(const float* sm, const float* W1, const float* b1,
    const float* W2, const float* b2, const float* W3, const float* b3, float* out) {
  __shared__ float nf[384];
  __shared__ float y1[192];
  __shared__ float y2[96];
  __shared__ float z[2];
  int t = threadIdx.x;
  int g = t / 128, j = t % 128;
  nf[t] = (j < 64) ? sm[g*64 + j] * (1.0f/(float)N)
                   : __int_as_float(((const int*)sm)[192 + g*64 + (j-64)]);
  __syncthreads();
  if (t < 192){
    float a = b1[t];
    for (int k=0;k<384;k++) a = fmaf(nf[k], W1[(size_t)k*192 + t], a);
    y1[t] = a > 0.f ? a : 0.f;
  }
  __syncthreads();
  if (t < 96){
    float a = b2[t];
    for (int k=0;k<192;k++) a = fmaf(y1[k], W2[(size_t)k*96 + t], a);
    y2[t] = a > 0.f ? a : 0.f;
  }
  __syncthreads();
  if (t < 2){
    float a = b3[t];
    for (int k=0;k<96;k++) a = fmaf(y2[k], W3[k*2 + t], a);
    z[t] = a;
  }
  __syncthreads();
  if (t == 0){
    float m = fmaxf(z[0], z[1]);
    float l = m + logf(__expf(z[0]-m) + __expf(z[1]-m));
    out[0] = z[0] - l;
    out[1] = z[1] - l;
  }
}

extern "C" void kernel_launch(void* const* d_in, const int* in_sizes, int n_in,
                              void* d_out, int out_size, void* d_ws, size_t ws_size,
                              hipStream_t stream) {
  const float* x_s  = (const float*)d_in[0];
  const float* x_g  = (const float*)d_in[1];
  const float* x_t  = (const float*)d_in[2];
  const float* Wc_s = (const float*)d_in[3];
  const float* bc_s = (const float*)d_in[4];
  const float* Wc_g = (const float*)d_in[5];
  const float* bc_g = (const float*)d_in[6];
  const float* Wc_t = (const float*)d_in[7];
  const float* bc_t = (const float*)d_in[8];
  const float* Wx   = (const float*)d_in[9];
  const float* bx   = (const float*)d_in[10];
  const float* Wgat = (const float*)d_in[11];
  const float* al   = (const float*)d_in[12];
  const float* ar   = (const float*)d_in[13];
  const float* bgat = (const float*)d_in[14];
  const float* W1   = (const float*)d_in[15];
  const float* b1   = (const float*)d_in[16];
  const float* W2   = (const float*)d_in[17];
  const float* b2   = (const float*)d_in[18];
  const float* W3   = (const float*)d_in[19];
  const float* b3   = (const float*)d_in[20];
  const int* src_s  = (const int*)d_in[21];
  const int* dst_s  = (const int*)d_in[22];
  const int* src_g  = (const int*)d_in[23];
  const int* dst_g  = (const int*)d_in[24];
  const int* src_t  = (const int*)d_in[25];
  const int* dst_t  = (const int*)d_in[26];

  float* fb = (float*)d_ws;
  int*   ib = (int*)(fb + 3*GF);
  ushort_t* hb = (ushort_t*)(ib + 3*GI);
  float* sm = (float*)(hb + 3*GH);
  int*   pt = (int*)(sm + 384);              // 3*SCB scan partials
  int*   parts_ct = pt + 3*SCB + 64;         // 3*BPR*N
  int*   parts_no = parts_ct + (size_t)3*BPR*N;
  int*   off      = parts_no + (size_t)3*BPR*N;
  float* out = (float*)d_out;

  dim3 b256(256);
  int mmb = (N+63)/64;

  // graph prep: LDS-histogram counting sort (no global atomics)
  k_hist      <<<dim3(BPR, RNG, 3),  dim3(1024), 0, stream>>>(parts_ct, parts_no, src_s,dst_s, src_g,dst_g, src_t,dst_t);
  k_scan_local<<<dim3(SCB, 3),       dim3(1024), 0, stream>>>(ib, pt, parts_ct);
  k_scan_part <<<dim3(3),              dim3(64), 0, stream>>>(pt);
  k_scan_apply<<<dim3(SCB, 3),       dim3(1024), 0, stream>>>(fb, ib, pt, parts_no);
  k_slice_off <<<dim3((N+255)/256, 3),     b256, 0, stream>>>(ib, parts_ct, off);
  k_scatter_r <<<dim3(BPR, RNG, 3),  dim3(1024), 0, stream>>>(ib, off, src_s,dst_s, src_g,dst_g, src_t,dst_t);
  k_copyx     <<<dim3((N*H/4+255)/256, 3), b256, 0, stream>>>(fb, x_s, x_g, x_t);

  for (int it = 0; it < 2; ++it) {
    k_mm_gcn  <<<dim3(mmb, 3),     b256, 0, stream>>>(fb, hb, Wc_s + it*4096, Wc_g + it*4096, Wc_t + it*4096, sm);
    k_gcn_agg <<<dim3(NWAVE/4, 3), b256, 0, stream>>>(fb, hb, ib, bc_s, bc_g, bc_t, it, sm, 1);
    k_exchange<<<dim3(3), dim3(64), 0, stream>>>(fb, hb, sm, Wx, bx, Wgat, al, it);
    k_mm_gat  <<<dim3(mmb, 3),     b256, 0, stream>>>(fb, hb, Wgat, al, ar);
    k_gat_prep<<<dim3(NWAVE/4, 3), b256, 0, stream>>>(fb, ib);
    k_gat_agg <<<dim3(NWAVE/4, 3), b256, 0, stream>>>(fb, hb, ib, bgat);
  }

  // final layer readouts + MLP head (x write skipped — only readout consumed)
  k_mm_gcn  <<<dim3(mmb, 3),     b256, 0, stream>>>(fb, hb, Wc_s + 2*4096, Wc_g + 2*4096, Wc_t + 2*4096, sm);
  k_gcn_agg <<<dim3(NWAVE/4, 3), b256, 0, stream>>>(fb, hb, ib, bc_s, bc_g, bc_t, 2, sm, 0);
  k_mlp     <<<1, 384, 0, stream>>>(sm, W1, b1, W2, b2, W3, b3, out);
}

// Round 14
// 1085.891 us; speedup vs baseline: 1.3384x; 1.0972x over previous
//
#include <hip/hip_runtime.h>
#include <math.h>

constexpr int N = 50000;
constexpr int E = 800000;
constexpr int H = 64;
constexpr int NWAVE = 12500;          // N/4 nodes-per-wave mapping (4 nodes per wave)
constexpr int SCB = 49;               // scan blocks per graph: 49*1024 >= N
constexpr int RNG = 8;                // histogram ranges per graph
constexpr int BPR = 8;                // edge slices per graph
constexpr int BINS = N / RNG;         // 6250 bins per range
constexpr int ES   = E / BPR;         // 100000 edges per slice

typedef unsigned short ushort_t;
typedef unsigned int uint_t;
typedef unsigned char uchar_t;
typedef float fl2 __attribute__((ext_vector_type(2)));
typedef float fl4 __attribute__((ext_vector_type(4)));

// ---- workspace layout (element offsets) ----
constexpr size_t X_OFF    = 0;                          // N*H
constexpr size_t NO_OFF   = X_OFF + (size_t)N*H;        // N   deg_out^-1/2
constexpr size_t NI_OFF   = NO_OFF + N;                 // N   deg_in^-1/2
constexpr size_t EL_OFF   = NI_OFF + N;                 // N+1 GAT el (incl supernode)
constexpr size_t ER_OFF   = EL_OFF + (N+1);             // N   GAT er
constexpr size_t EE_OFF   = ER_OFF + N;                 // E   per-edge exp(e) (CSR order)
constexpr size_t IS_OFF   = EE_OFF + E;                 // N   1/softmax-denominator
constexpr size_t ASLF_OFF = IS_OFF + N;                 // N   self-loop numerator
constexpr size_t ASUP_OFF = ASLF_OFF + N;               // N   supernode numerator
constexpr size_t GF = ((ASUP_OFF + N + 255)/256)*256;

constexpr size_t RP_OFF = 0;                            // N+1 row_ptr (CSR by dst)
constexpr size_t CT_OFF = RP_OFF + (N+1);               // N   in-degree count
constexpr size_t SS_OFF = CT_OFF + N;                   // E   src sorted by dst
constexpr size_t GI = ((SS_OFF + E + 255)/256)*256;

// per-graph fp8 h block: 64 B per row (64 x e4m3 = 16 uints); row N = supernode
constexpr size_t GH = (size_t)(N+1)*64;                 // bytes

// fp8 helpers: HW RNE pack/unpack (OCP e4m3 on gfx950)
__device__ inline uint_t f8pack4(float a, float b, float c, float d){
  int r = __builtin_amdgcn_cvt_pk_fp8_f32(a, b, 0, false);
  r = __builtin_amdgcn_cvt_pk_fp8_f32(c, d, r, true);
  return (uint_t)r;
}
__device__ inline fl4 f8up4(uint_t v){
  fl2 lo = __builtin_amdgcn_cvt_pk_f32_fp8((int)v, false);
  fl2 hi = __builtin_amdgcn_cvt_pk_f32_fp8((int)v, true);
  fl4 r; r.x = lo.x; r.y = lo.y; r.z = hi.x; r.w = hi.y;
  return r;
}

// ---- prep: range-partitioned LDS histograms, zero global atomics ----
__global__ __launch_bounds__(1024) void k_hist(int* parts_ct, int* parts_no,
    const int* s0,const int* d0,const int* s1,const int* d1,const int* s2,const int* d2) {
  int sl = blockIdx.x, r = blockIdx.y, g = blockIdx.z;
  const int* s = g==0?s0:(g==1?s1:s2);
  const int* d = g==0?d0:(g==1?d1:d2);
  __shared__ int hc[BINS];
  __shared__ int hn[BINS];
  for (int i=threadIdx.x;i<BINS;i+=1024){ hc[i]=0; hn[i]=0; }
  __syncthreads();
  int lo = r*BINS, hi = lo+BINS;
  int e0 = sl*ES, e1 = e0+ES;
  for (int e=e0+threadIdx.x; e<e1; e+=1024){
    int ds = d[e], sr = s[e];
    if (ds>=lo && ds<hi) atomicAdd(&hc[ds-lo],1);
    if (sr>=lo && sr<hi) atomicAdd(&hn[sr-lo],1);
  }
  __syncthreads();
  size_t base = ((size_t)g*BPR + sl)*N + lo;
  for (int i=threadIdx.x;i<BINS;i+=1024){
    parts_ct[base+i]=hc[i];
    parts_no[base+i]=hn[i];
  }
}

// ---- hierarchical exclusive scan of cnt -> rp (all parallel) ----
__global__ __launch_bounds__(1024) void k_scan_local(int* ib, int* pt, const int* parts_ct) {
  int g = blockIdx.y;
  int* ig = ib + (size_t)g*GI;
  int i = blockIdx.x*1024 + threadIdx.x;
  int c = 0;
  if (i < N){
    #pragma unroll
    for (int s=0;s<BPR;s++) c += parts_ct[((size_t)g*BPR+s)*N + i];
    ig[CT_OFF + i] = c;
  }
  __shared__ int sh[1024];
  sh[threadIdx.x] = c; __syncthreads();
  #pragma unroll
  for (int off=1; off<1024; off<<=1){
    int t = (threadIdx.x>=off) ? sh[threadIdx.x-off] : 0;
    __syncthreads();
    sh[threadIdx.x] += t;
    __syncthreads();
  }
  if (i < N) ig[RP_OFF + i] = sh[threadIdx.x] - c;       // local exclusive
  if (threadIdx.x == 1023) pt[g*SCB + blockIdx.x] = sh[1023];
}

__global__ void k_scan_part(int* pt) {
  int g = blockIdx.x;
  __shared__ int sh[SCB];
  int t = threadIdx.x;
  if (t < SCB) sh[t] = pt[g*SCB + t];
  __syncthreads();
  if (t == 0){
    int run = 0;
    for (int b=0;b<SCB;b++){ int c = sh[b]; sh[b] = run; run += c; }
  }
  __syncthreads();
  if (t < SCB) pt[g*SCB + t] = sh[t];
}

__global__ __launch_bounds__(1024) void k_scan_apply(float* fb, int* ib, const int* pt,
                                                     const int* parts_no) {
  int g = blockIdx.y;
  float* fg = fb + (size_t)g*GF;
  int* ig = ib + (size_t)g*GI;
  int i = blockIdx.x*1024 + threadIdx.x;
  if (i >= N) return;
  int base = pt[g*SCB + blockIdx.x];
  int r = ig[RP_OFF + i] + base;
  ig[RP_OFF + i] = r;
  int c = ig[CT_OFF + i];
  int o = 0;
  #pragma unroll
  for (int s=0;s<BPR;s++) o += parts_no[((size_t)g*BPR+s)*N + i];
  fg[NI_OFF + i] = rsqrtf((float)(c+1));                 // +1 self loop
  fg[NO_OFF + i] = rsqrtf((float)(o+1));
  if (i == N-1) ig[RP_OFF + N] = r + c;
}

// per-(slice,bin) exclusive prefix over slices -> exact scatter offsets
__global__ __launch_bounds__(256) void k_slice_off(const int* ib, const int* parts_ct, int* off) {
  int g = blockIdx.y;
  int i = blockIdx.x*256 + threadIdx.x;
  if (i >= N) return;
  int base = ib[(size_t)g*GI + RP_OFF + i];
  #pragma unroll
  for (int s=0;s<BPR;s++){
    size_t idx = ((size_t)g*BPR+s)*N + i;
    off[idx] = base;
    base += parts_ct[idx];
  }
}

// scatter: LDS cursors per range, plain scattered store (no global atomics)
__global__ __launch_bounds__(1024) void k_scatter_r(int* ib, const int* off,
    const int* s0,const int* d0,const int* s1,const int* d1,const int* s2,const int* d2) {
  int sl = blockIdx.x, r = blockIdx.y, g = blockIdx.z;
  const int* s = g==0?s0:(g==1?s1:s2);
  const int* d = g==0?d0:(g==1?d1:d2);
  int* ss = ib + (size_t)g*GI + SS_OFF;
  __shared__ int cur[BINS];
  int lo = r*BINS;
  size_t ob = ((size_t)g*BPR + sl)*N + lo;
  for (int i=threadIdx.x;i<BINS;i+=1024) cur[i] = off[ob+i];
  __syncthreads();
  int e0 = sl*ES, e1 = e0+ES;
  for (int e=e0+threadIdx.x; e<e1; e+=1024){
    int ds = d[e];
    if (ds>=lo && ds<lo+BINS){
      int pos = atomicAdd(&cur[ds-lo],1);
      ss[pos] = s[e];
    }
  }
}

__global__ __launch_bounds__(256) void k_copyx(float* fb, const float* x0,const float* x1,const float* x2) {
  int i = blockIdx.x*256 + threadIdx.x;
  int g = blockIdx.y;
  const float* x = g==0?x0:(g==1?x1:x2);
  if (i < N*H/4) {
    ((float4*)(fb + (size_t)g*GF + X_OFF))[i] = ((const float4*)x)[i];
  }
}

// Tiled matmul: 64 rows/block, 4 threads/row (q = 16-col group), acc[16].
// h = fp8( (x @ W) * no[row] ) -> 64 B/row. Block (0,0) zeroes readout accs.
__global__ __launch_bounds__(256) void k_mm_gcn(float* fb, uchar_t* hb,
    const float* W0,const float* W1,const float* W2, float* sm) {
  if (blockIdx.x==0 && blockIdx.y==0){
    for (int i=threadIdx.x;i<384;i+=256) sm[i]=0.f;
  }
  int g = blockIdx.y;
  const float* W = g==0?W0:(g==1?W1:W2);
  __shared__ float Ws[64*64];
  __shared__ float Xs[64*65];
  float* fg = fb + (size_t)g*GF;
  int row0 = blockIdx.x*64;
  for (int i=threadIdx.x; i<4096; i+=256) Ws[i] = W[i];
  int r = threadIdx.x>>2, q = threadIdx.x&3;
  int row = row0 + r;
  int rowc = row < N ? row : N-1;
  {
    const float4* xr = (const float4*)(fg + X_OFF + (size_t)rowc*64) + q*4;
    float* xd = Xs + r*65 + q*16;
    #pragma unroll
    for (int c=0;c<4;c++){ float4 v = xr[c]; xd[4*c]=v.x; xd[4*c+1]=v.y; xd[4*c+2]=v.z; xd[4*c+3]=v.w; }
  }
  __syncthreads();
  float acc[16];
  #pragma unroll
  for (int j=0;j<16;j++) acc[j]=0.f;
  const float* xrow = Xs + r*65;
  #pragma unroll 8
  for (int k=0;k<64;k++){
    float xk = xrow[k];
    const float* wr = Ws + k*64 + q*16;
    #pragma unroll
    for (int j=0;j<16;j++) acc[j] = fmaf(xk, wr[j], acc[j]);
  }
  if (row >= N) return;
  float sc = fg[NO_OFF + row];
  uint_t pk[4];
  #pragma unroll
  for (int j=0;j<4;j++)
    pk[j] = f8pack4(acc[4*j]*sc, acc[4*j+1]*sc, acc[4*j+2]*sc, acc[4*j+3]*sc);
  *(uint4*)(hb + (size_t)g*GH + (size_t)row*64 + q*16) = *(const uint4*)pk;
}

// Same tiling; h = fp8(x @ Wgat[g]); el/er via quad shfl reduce.
__global__ __launch_bounds__(256) void k_mm_gat(float* fb, uchar_t* hb,
    const float* Wgat, const float* al, const float* ar) {
  int g = blockIdx.y;
  const float* W = Wgat + (size_t)g*4096;
  __shared__ float Ws[64*64];
  __shared__ float Xs[64*65];
  __shared__ float als[64], ars[64];
  float* fg = fb + (size_t)g*GF;
  int row0 = blockIdx.x*64;
  for (int i=threadIdx.x; i<4096; i+=256) Ws[i] = W[i];
  if (threadIdx.x < 64){ als[threadIdx.x] = al[g*64+threadIdx.x]; ars[threadIdx.x] = ar[g*64+threadIdx.x]; }
  int r = threadIdx.x>>2, q = threadIdx.x&3;
  int row = row0 + r;
  int rowc = row < N ? row : N-1;
  {
    const float4* xr = (const float4*)(fg + X_OFF + (size_t)rowc*64) + q*4;
    float* xd = Xs + r*65 + q*16;
    #pragma unroll
    for (int c=0;c<4;c++){ float4 v = xr[c]; xd[4*c]=v.x; xd[4*c+1]=v.y; xd[4*c+2]=v.z; xd[4*c+3]=v.w; }
  }
  __syncthreads();
  float acc[16];
  #pragma unroll
  for (int j=0;j<16;j++) acc[j]=0.f;
  const float* xrow = Xs + r*65;
  #pragma unroll 8
  for (int k=0;k<64;k++){
    float xk = xrow[k];
    const float* wr = Ws + k*64 + q*16;
    #pragma unroll
    for (int j=0;j<16;j++) acc[j] = fmaf(xk, wr[j], acc[j]);
  }
  float el = 0.f, er = 0.f;
  #pragma unroll
  for (int j=0;j<16;j++){ el = fmaf(acc[j], als[q*16+j], el); er = fmaf(acc[j], ars[q*16+j], er); }
  el += __shfl_xor(el,1); el += __shfl_xor(el,2);
  er += __shfl_xor(er,1); er += __shfl_xor(er,2);
  if (row >= N) return;
  uint_t pk[4];
  #pragma unroll
  for (int j=0;j<4;j++)
    pk[j] = f8pack4(acc[4*j], acc[4*j+1], acc[4*j+2], acc[4*j+3]);
  *(uint4*)(hb + (size_t)g*GH + (size_t)row*64 + q*16) = *(const uint4*)pk;
  if (q == 0){
    fg[EL_OFF + row] = el;
    fg[ER_OFF + row] = er;
  }
}

// GCN aggregate, merged over graphs. fp8 rows, 16 lanes/row, dword/lane:
// one gather instr = 4 edges, 4 lines, 4 addr/edge -> 16x fewer addresses.
// lane = (q = edge slot 0-3, u = uint 0-15). Edge idx distributed via shfl.
__global__ __launch_bounds__(256) void k_gcn_agg(float* fb, const uchar_t* hb, const int* ib,
    const float* b0, const float* b1, const float* b2, int lay, float* sm, int writex) {
  int g = blockIdx.y;
  const float* b = (g==0?b0:(g==1?b1:b2)) + lay*64;
  float* fg = fb + (size_t)g*GF;
  const uint_t* hu = (const uint_t*)(hb + (size_t)g*GH);  // 16 uints per row
  const int* ig = ib + (size_t)g*GI;
  int wave = threadIdx.x >> 6, lane = threadIdx.x & 63;
  int q = lane >> 4, u = lane & 15;
  int w = blockIdx.x*4 + wave;
  const int* rp = ig + RP_OFF;
  const int* ss = ig + SS_OFF;
  fl4 bl = ((const fl4*)b)[u];
  fl4 vs = {0.f,0.f,0.f,0.f}, vm = {0.f,0.f,0.f,0.f};
  __shared__ float ssum[4][64];
  __shared__ float smx[4][64];
  #pragma unroll
  for (int i=0;i<4;i++){
    int node = w + NWAVE*i;
    int s0 = rp[node], s1 = rp[node+1];
    fl4 a = {0.f,0.f,0.f,0.f};
    if (q == 0) a = f8up4(hu[(size_t)node*16 + u]);   // self loop (pre-scaled)
    int k = s0;
    for (; k + 16 <= s1; k += 16){
      int idxv = ss[k + (lane & 15)];
      int i0 = __shfl(idxv, q);
      int i1 = __shfl(idxv, q+4);
      int i2 = __shfl(idxv, q+8);
      int i3 = __shfl(idxv, q+12);
      uint_t v0 = hu[(size_t)i0*16 + u];
      uint_t v1 = hu[(size_t)i1*16 + u];
      uint_t v2 = hu[(size_t)i2*16 + u];
      uint_t v3 = hu[(size_t)i3*16 + u];
      a += (f8up4(v0) + f8up4(v1)) + (f8up4(v2) + f8up4(v3));
    }
    for (; k < s1; k += 4){
      int e = k + q;
      int ec = e < s1 ? e : s1-1;
      int idx = ss[ec];
      float wv = e < s1 ? 1.f : 0.f;
      fl4 f = f8up4(hu[(size_t)idx*16 + u]);
      a.x = fmaf(wv, f.x, a.x); a.y = fmaf(wv, f.y, a.y);
      a.z = fmaf(wv, f.z, a.z); a.w = fmaf(wv, f.w, a.w);
    }
    a.x += __shfl_xor(a.x,16); a.x += __shfl_xor(a.x,32);
    a.y += __shfl_xor(a.y,16); a.y += __shfl_xor(a.y,32);
    a.z += __shfl_xor(a.z,16); a.z += __shfl_xor(a.z,32);
    a.w += __shfl_xor(a.w,16); a.w += __shfl_xor(a.w,32);
    if (q == 0){
      float ni = fg[NI_OFF + node];
      fl4 v;
      v.x = fmaf(a.x, ni, bl.x); v.x = v.x > 0.f ? v.x : 0.f;
      v.y = fmaf(a.y, ni, bl.y); v.y = v.y > 0.f ? v.y : 0.f;
      v.z = fmaf(a.z, ni, bl.z); v.z = v.z > 0.f ? v.z : 0.f;
      v.w = fmaf(a.w, ni, bl.w); v.w = v.w > 0.f ? v.w : 0.f;
      if (writex) ((fl4*)(fg + X_OFF + (size_t)node*64))[u] = v;
      vs += v;
      vm.x = fmaxf(vm.x,v.x); vm.y = fmaxf(vm.y,v.y);
      vm.z = fmaxf(vm.z,v.z); vm.w = fmaxf(vm.w,v.w);
    }
  }
  if (q == 0){
    ((fl4*)ssum[wave])[u] = vs;
    ((fl4*)smx[wave])[u]  = vm;
  }
  __syncthreads();
  if (threadIdx.x < 64){
    int t = threadIdx.x;
    float s = ssum[0][t]+ssum[1][t]+ssum[2][t]+ssum[3][t];
    float mx = fmaxf(fmaxf(smx[0][t],smx[1][t]), fmaxf(smx[2][t],smx[3][t]));
    atomicAdd(&sm[g*64 + t], s);
    atomicMax((int*)sm + 192 + g*64 + t, __float_as_int(mx));  // v>=0: int order == float order
  }
}

// readout finalize + cross-graph feature exchange + supernode h row (fp8), el[N]
__global__ void k_exchange(float* fb, uchar_t* hb, float* sm, const float* Wx, const float* bx,
                           const float* Wgat, const float* al, int it) {
  int gt = blockIdx.x;     // target graph
  int t = threadIdx.x;     // 64 threads
  int src, widx;
  if ((it & 1) == 0){ src = (gt==0)?1:(gt==1)?2:0; widx = (gt==0)?1:(gt==1)?0:2; }
  else              { src = (gt==0)?2:(gt==1)?0:1; widx = (gt==0)?5:(gt==1)?3:4; }
  __shared__ float ro[128];
  __shared__ float f[64];
  __shared__ float red[64];
  __shared__ float hsb[64];
  ro[t]      = sm[src*64 + t] * (1.0f/(float)N);
  ro[64 + t] = __int_as_float(((int*)sm)[192 + src*64 + t]);
  __syncthreads();
  float a = bx[widx*64 + t];
  for (int k=0;k<128;k++) a = fmaf(ro[k], Wx[(size_t)widx*8192 + k*64 + t], a);
  a = a > 0.f ? a : 0.f;
  f[t] = a;
  __syncthreads();
  float* fg = fb + (size_t)gt*GF;
  float hs = 0.f;
  for (int k=0;k<64;k++) hs = fmaf(f[k], Wgat[(size_t)gt*4096 + k*64 + t], hs);
  hsb[t] = hs;
  red[t] = hs * al[gt*64 + t];
  __syncthreads();
  if (t < 16){
    uint_t r = f8pack4(hsb[4*t], hsb[4*t+1], hsb[4*t+2], hsb[4*t+3]);
    ((uint_t*)(hb + (size_t)gt*GH + (size_t)N*64))[t] = r;
  }
  if (t == 0){
    float e = 0.f;
    for (int k=0;k<64;k++) e += red[k];
    fg[EL_OFF + N] = e;                      // el for supernode
  }
}

// GAT softmax prep: wave per 4 nodes, lanes parallel over edges.
// Softmax computed without max-shift (|e| << 80, exact in fp32).
__global__ __launch_bounds__(256) void k_gat_prep(float* fb, const int* ib) {
  int g = blockIdx.y;
  float* fg = fb + (size_t)g*GF;
  const int* ig = ib + (size_t)g*GI;
  const int* rp = ig + RP_OFF;
  const int* ss = ig + SS_OFF;
  const float* el = fg + EL_OFF;
  float* ee = fg + EE_OFF;
  int wave = threadIdx.x>>6, lane = threadIdx.x&63;
  int w = blockIdx.x*4 + wave;
  float elsup = el[N];
  #pragma unroll
  for (int i=0;i<4;i++){
    int node = w + NWAVE*i;
    float eri = fg[ER_OFF + node];
    int s0 = rp[node], s1 = rp[node+1];
    float s = 0.f;
    for (int k=s0; k<s1; k+=64){
      int e = k + lane;
      float t = 0.f;
      if (e < s1){
        float x = el[ss[e]] + eri;
        x = x >= 0.f ? x : 0.2f*x;
        t = __expf(x);
        ee[e] = t;
      }
      s += t;
    }
    #pragma unroll
    for (int m=1;m<64;m<<=1) s += __shfl_xor(s,m);
    if (lane == 0){
      float eself = el[node] + eri; eself = eself >= 0.f ? eself : 0.2f*eself;
      float esup  = elsup + eri;    esup  = esup  >= 0.f ? esup  : 0.2f*esup;
      float ts = __expf(eself), tu = __expf(esup);
      s += ts + tu;
      fg[IS_OFF + node]   = 1.0f / s;
      fg[ASLF_OFF + node] = ts;
      fg[ASUP_OFF + node] = tu;
    }
  }
}

// GAT aggregation, merged: same 4-edge/instr fp8 scheme with shfl-distributed
// per-edge weights; slot 0 adds self-loop, slot 1 adds supernode.
__global__ __launch_bounds__(256) void k_gat_agg(float* fb, const uchar_t* hb, const int* ib,
    const float* bgat) {
  int g = blockIdx.y;
  float* fg = fb + (size_t)g*GF;
  const uint_t* hu = (const uint_t*)(hb + (size_t)g*GH);
  const int* ig = ib + (size_t)g*GI;
  int wave = threadIdx.x >> 6, lane = threadIdx.x & 63;
  int q = lane >> 4, u = lane & 15;
  int w = blockIdx.x*4 + wave;
  const int* rp = ig + RP_OFF;
  const int* ss = ig + SS_OFF;
  const float* ee = fg + EE_OFF;
  fl4 bg = ((const fl4*)(bgat + g*64))[u];
  fl4 supf = f8up4(hu[(size_t)N*16 + u]);
  #pragma unroll
  for (int i=0;i<4;i++){
    int node = w + NWAVE*i;
    int s0 = rp[node], s1 = rp[node+1];
    fl4 a = {0.f,0.f,0.f,0.f};
    if (q == 0){
      float aslf = fg[ASLF_OFF + node];
      fl4 f = f8up4(hu[(size_t)node*16 + u]);
      a.x = aslf*f.x; a.y = aslf*f.y; a.z = aslf*f.z; a.w = aslf*f.w;
    } else if (q == 1){
      float asup = fg[ASUP_OFF + node];
      a.x = asup*supf.x; a.y = asup*supf.y; a.z = asup*supf.z; a.w = asup*supf.w;
    }
    int k = s0;
    for (; k + 16 <= s1; k += 16){
      int idxv = ss[k + (lane & 15)];
      float wtv = ee[k + (lane & 15)];
      int i0 = __shfl(idxv, q);
      int i1 = __shfl(idxv, q+4);
      int i2 = __shfl(idxv, q+8);
      int i3 = __shfl(idxv, q+12);
      float w0 = __shfl(wtv, q);
      float w1 = __shfl(wtv, q+4);
      float w2 = __shfl(wtv, q+8);
      float w3 = __shfl(wtv, q+12);
      uint_t v0 = hu[(size_t)i0*16 + u];
      uint_t v1 = hu[(size_t)i1*16 + u];
      uint_t v2 = hu[(size_t)i2*16 + u];
      uint_t v3 = hu[(size_t)i3*16 + u];
      fl4 f0=f8up4(v0), f1=f8up4(v1), f2=f8up4(v2), f3=f8up4(v3);
      a.x += (fmaf(w0,f0.x, w1*f1.x)) + (fmaf(w2,f2.x, w3*f3.x));
      a.y += (fmaf(w0,f0.y, w1*f1.y)) + (fmaf(w2,f2.y, w3*f3.y));
      a.z += (fmaf(w0,f0.z, w1*f1.z)) + (fmaf(w2,f2.z, w3*f3.z));
      a.w += (fmaf(w0,f0.w, w1*f1.w)) + (fmaf(w2,f2.w, w3*f3.w));
    }
    for (; k < s1; k += 4){
      int e = k + q;
      int ec = e < s1 ? e : s1-1;
      int idx = ss[ec];
      float wv = e < s1 ? ee[ec] : 0.f;
      fl4 f = f8up4(hu[(size_t)idx*16 + u]);
      a.x = fmaf(wv, f.x, a.x); a.y = fmaf(wv, f.y, a.y);
      a.z = fmaf(wv, f.z, a.z); a.w = fmaf(wv, f.w, a.w);
    }
    a.x += __shfl_xor(a.x,16); a.x += __shfl_xor(a.x,32);
    a.y += __shfl_xor(a.y,16); a.y += __shfl_xor(a.y,32);
    a.z += __shfl_xor(a.z,16); a.z += __shfl_xor(a.z,32);
    a.w += __shfl_xor(a.w,16); a.w += __shfl_xor(a.w,32);
    if (q == 0){
      float is = fg[IS_OFF + node];
      fl4 v;
      v.x = fmaf(a.x, is, bg.x); v.y = fmaf(a.y, is, bg.y);
      v.z = fmaf(a.z, is, bg.z); v.w = fmaf(a.w, is, bg.w);
      ((fl4*)(fg + X_OFF + (size_t)node*64))[u] = v;
    }
  }
}

__global__ __launch_bounds__(384) void k_mlp(const float* sm, const float* W1, const float* b1,
    const float* W2, const float* b2, const float* W3, const float* b3, float* out) {
  __shared__ float nf[384];
  __shared__ float y1[192];
  __shared__ float y2[96];
  __shared__ float z[2];
  int t = threadIdx.x;
  int g = t / 128, j = t % 128;
  nf[t] = (j < 64) ? sm[g*64 + j] * (1.0f/(float)N)
                   : __int_as_float(((const int*)sm)[192 + g*64 + (j-64)]);
  __syncthreads();
  if (t < 192){
    float a = b1[t];
    for (int k=0;k<384;k++) a = fmaf(nf[k], W1[(size_t)k*192 + t], a);
    y1[t] = a > 0.f ? a : 0.f;
  }
  __syncthreads();
  if (t < 96){
    float a = b2[t];
    for (int k=0;k<192;k++) a = fmaf(y1[k], W2[(size_t)k*96 + t], a);
    y2[t] = a > 0.f ? a : 0.f;
  }
  __syncthreads();
  if (t < 2){
    float a = b3[t];
    for (int k=0;k<96;k++) a = fmaf(y2[k], W3[k*2 + t], a);
    z[t] = a;
  }
  __syncthreads();
  if (t == 0){
    float m = fmaxf(z[0], z[1]);
    float l = m + logf(__expf(z[0]-m) + __expf(z[1]-m));
    out[0] = z[0] - l;
    out[1] = z[1] - l;
  }
}

extern "C" void kernel_launch(void* const* d_in, const int* in_sizes, int n_in,
                              void* d_out, int out_size, void* d_ws, size_t ws_size,
                              hipStream_t stream) {
  const float* x_s  = (const float*)d_in[0];
  const float* x_g  = (const float*)d_in[1];
  const float* x_t  = (const float*)d_in[2];
  const float* Wc_s = (const float*)d_in[3];
  const float* bc_s = (const float*)d_in[4];
  const float* Wc_g = (const float*)d_in[5];
  const float* bc_g = (const float*)d_in[6];
  const float* Wc_t = (const float*)d_in[7];
  const float* bc_t = (const float*)d_in[8];
  const float* Wx   = (const float*)d_in[9];
  const float* bx   = (const float*)d_in[10];
  const float* Wgat = (const float*)d_in[11];
  const float* al   = (const float*)d_in[12];
  const float* ar   = (const float*)d_in[13];
  const float* bgat = (const float*)d_in[14];
  const float* W1   = (const float*)d_in[15];
  const float* b1   = (const float*)d_in[16];
  const float* W2   = (const float*)d_in[17];
  const float* b2   = (const float*)d_in[18];
  const float* W3   = (const float*)d_in[19];
  const float* b3   = (const float*)d_in[20];
  const int* src_s  = (const int*)d_in[21];
  const int* dst_s  = (const int*)d_in[22];
  const int* src_g  = (const int*)d_in[23];
  const int* dst_g  = (const int*)d_in[24];
  const int* src_t  = (const int*)d_in[25];
  const int* dst_t  = (const int*)d_in[26];

  float* fb = (float*)d_ws;
  int*   ib = (int*)(fb + 3*GF);
  uchar_t* hb = (uchar_t*)(ib + 3*GI);
  float* sm = (float*)(hb + 3*GH);
  int*   pt = (int*)(sm + 384);              // 3*SCB scan partials
  int*   parts_ct = pt + 3*SCB + 64;         // 3*BPR*N
  int*   parts_no = parts_ct + (size_t)3*BPR*N;
  int*   off      = parts_no + (size_t)3*BPR*N;
  float* out = (float*)d_out;

  dim3 b256(256);
  int mmb = (N+63)/64;

  // graph prep: LDS-histogram counting sort (no global atomics)
  k_hist      <<<dim3(BPR, RNG, 3),  dim3(1024), 0, stream>>>(parts_ct, parts_no, src_s,dst_s, src_g,dst_g, src_t,dst_t);
  k_scan_local<<<dim3(SCB, 3),       dim3(1024), 0, stream>>>(ib, pt, parts_ct);
  k_scan_part <<<dim3(3),              dim3(64), 0, stream>>>(pt);
  k_scan_apply<<<dim3(SCB, 3),       dim3(1024), 0, stream>>>(fb, ib, pt, parts_no);
  k_slice_off <<<dim3((N+255)/256, 3),     b256, 0, stream>>>(ib, parts_ct, off);
  k_scatter_r <<<dim3(BPR, RNG, 3),  dim3(1024), 0, stream>>>(ib, off, src_s,dst_s, src_g,dst_g, src_t,dst_t);
  k_copyx     <<<dim3((N*H/4+255)/256, 3), b256, 0, stream>>>(fb, x_s, x_g, x_t);

  for (int it = 0; it < 2; ++it) {
    k_mm_gcn  <<<dim3(mmb, 3),     b256, 0, stream>>>(fb, hb, Wc_s + it*4096, Wc_g + it*4096, Wc_t + it*4096, sm);
    k_gcn_agg <<<dim3(NWAVE/4, 3), b256, 0, stream>>>(fb, hb, ib, bc_s, bc_g, bc_t, it, sm, 1);
    k_exchange<<<dim3(3), dim3(64), 0, stream>>>(fb, hb, sm, Wx, bx, Wgat, al, it);
    k_mm_gat  <<<dim3(mmb, 3),     b256, 0, stream>>>(fb, hb, Wgat, al, ar);
    k_gat_prep<<<dim3(NWAVE/4, 3), b256, 0, stream>>>(fb, ib);
    k_gat_agg <<<dim3(NWAVE/4, 3), b256, 0, stream>>>(fb, hb, ib, bgat);
  }

  // final layer readouts + MLP head (x write skipped — only readout consumed)
  k_mm_gcn  <<<dim3(mmb, 3),     b256, 0, stream>>>(fb, hb, Wc_s + 2*4096, Wc_g + 2*4096, Wc_t + 2*4096, sm);
  k_gcn_agg <<<dim3(NWAVE/4, 3), b256, 0, stream>>>(fb, hb, ib, bc_s, bc_g, bc_t, 2, sm, 0);
  k_mlp     <<<1, 384, 0, stream>>>(sm, W1, b1, W2, b2, W3, b3, out);
}